// Round 1
// baseline (2213.150 us; speedup 1.0000x reference)
//
#include <hip/hip_runtime.h>
#include <math.h>

#define HQn 16
#define HKn 4
#define Gn 4
#define Dn 128
#define DVn 128
#define STRIDEn 16
#define CBLKn 32
#define SBLKn 64
#define NSELn 16
#define WINn 512
#define SMAX 2048

// ---------------------------------------------------------------------------
// ck[h][c][e] = sum_{w,d} src[(c*16+w)*HK*128 + h*128 + d] * W[(w*128+d)*128 + e]
// One block: 4 consecutive c's for one head. 128 threads = e dimension.
// ---------------------------------------------------------------------------
__global__ __launch_bounds__(128)
void nsa_compress(const float* __restrict__ src, const float* __restrict__ W,
                  float* __restrict__ dst, int S, int C) {
  __shared__ float lk[80 * Dn];  // rows [c0*16, c0*16+80) of this head
  const int tid = threadIdx.x;
  const int c0 = blockIdx.x * 4;
  const int h  = blockIdx.y;
  const int r0 = c0 * STRIDEn;
  for (int i = tid; i < 80 * Dn; i += 128) {
    int row = i >> 7, col = i & 127;
    int gr = r0 + row;
    lk[i] = (gr < S) ? src[(gr * HKn + h) * Dn + col] : 0.f;
  }
  __syncthreads();
  float acc0 = 0.f, acc1 = 0.f, acc2 = 0.f, acc3 = 0.f;
  // f = w*128 + d ; lds offset for chunk cc is cc*(16*128) + f
#pragma unroll 4
  for (int f = 0; f < CBLKn * Dn; ++f) {
    float wv = W[f * Dn + tid];
    acc0 += lk[f] * wv;
    acc1 += lk[f + 1 * STRIDEn * Dn] * wv;
    acc2 += lk[f + 2 * STRIDEn * Dn] * wv;
    acc3 += lk[f + 3 * STRIDEn * Dn] * wv;
  }
  if (c0 + 0 < C) dst[(h * C + c0 + 0) * Dn + tid] = acc0;
  if (c0 + 1 < C) dst[(h * C + c0 + 1) * Dn + tid] = acc1;
  if (c0 + 2 < C) dst[(h * C + c0 + 2) * Dn + tid] = acc2;
  if (c0 + 3 < C) dst[(h * C + c0 + 3) * Dn + tid] = acc3;
}

// ---------------------------------------------------------------------------
// One block per (row s, kv-head hk). 256 threads (4 waves). Handles all G=4
// query heads of the group. Does: compressed attention + selection top-k +
// selected/window attention + gating, writes final output row.
// ---------------------------------------------------------------------------
__global__ __launch_bounds__(256)
void nsa_main(const float* __restrict__ q, const float* __restrict__ k,
              const float* __restrict__ v, const float* __restrict__ ck,
              const float* __restrict__ cv, const float* __restrict__ Wg,
              const float* __restrict__ bg, float* __restrict__ out,
              int S, int C, int NBLK) {
  __shared__ float qs[Gn][Dn];
  __shared__ float lw[Gn][SMAX];     // raw logits, later combined weights
  __shared__ float pcs[Gn][128];     // compressed probs (c dim, padded)
  __shared__ float score_s[128];     // sum over g of pcs
  __shared__ float cmp_s[Gn][DVn];   // compressed-path output
  __shared__ float gate_s[Gn][3];
  __shared__ float msum_s[Gn][4];    // m_sel, inv_d_sel, m_win, inv_d_win
  __shared__ unsigned long long selmask_s;

  const int s    = blockIdx.x;
  const int hk   = blockIdx.y;
  const int tid  = threadIdx.x;
  const int lane = tid & 63;
  const int wid  = tid >> 6;
  const float scale = 0.08838834764831845f;  // 1/sqrt(128)

  for (int i = tid; i < Gn * Dn; i += 256) {
    int g = i >> 7, d = i & 127;
    qs[g][d] = q[(s * HQn + hk * Gn + g) * Dn + d];
  }
  __syncthreads();

  // ---- gates: sigmoid(q . Wg + bg), 12 small dots ----
  if (tid < Gn * 3) {
    int g = tid / 3, j = tid % 3;
    float a = bg[j];
    for (int d = 0; d < Dn; ++d) a += qs[g][d] * Wg[d * 3 + j];
    gate_s[g][j] = 1.f / (1.f + expf(-a));
  }

  int cmax = (s >= CBLKn - 1) ? ((s - (CBLKn - 1)) / STRIDEn + 1) : 0;
  if (cmax > C) cmax = C;

  // ---- compressed logits: thread c computes 4 dots of length 128 ----
  if (tid < 128 && tid < cmax) {
    const float* ckr = ck + (hk * C + tid) * Dn;
    float a0 = 0, a1 = 0, a2 = 0, a3 = 0;
    for (int d = 0; d < Dn; ++d) {
      float kv = ckr[d];
      a0 += qs[0][d] * kv; a1 += qs[1][d] * kv;
      a2 += qs[2][d] * kv; a3 += qs[3][d] * kv;
    }
    pcs[0][tid] = a0 * scale; pcs[1][tid] = a1 * scale;
    pcs[2][tid] = a2 * scale; pcs[3][tid] = a3 * scale;
  }
  __syncthreads();

  // ---- per-g masked softmax over c (wave wid handles g = wid) ----
  {
    const int g = wid;
    float m = -INFINITY;
    for (int cc = lane; cc < 128; cc += 64)
      if (cc < cmax) m = fmaxf(m, pcs[g][cc]);
    for (int off = 32; off; off >>= 1) m = fmaxf(m, __shfl_xor(m, off));
    float ssum = 0.f;
    for (int cc = lane; cc < 128; cc += 64) {
      if (cc < cmax) {
        float e = expf(pcs[g][cc] - m);
        pcs[g][cc] = e;
        ssum += e;
      }
    }
    for (int off = 32; off; off >>= 1) ssum += __shfl_xor(ssum, off);
    float inv = 1.f / fmaxf(ssum, 1e-20f);
    for (int cc = lane; cc < 128; cc += 64)
      pcs[g][cc] = (cc < cmax) ? pcs[g][cc] * inv : 0.f;
  }
  __syncthreads();

  if (tid < 128)
    score_s[tid] = pcs[0][tid] + pcs[1][tid] + pcs[2][tid] + pcs[3][tid];

  // ---- compressed-path PV: thread (half, e) does 2 g's ----
  {
    const int e = tid & 127, half = tid >> 7;
    const int g0 = 2 * half, g1 = g0 + 1;
    float a0 = 0.f, a1 = 0.f;
    for (int cc = 0; cc < cmax; ++cc) {
      float vv = cv[(hk * C + cc) * DVn + e];
      a0 += pcs[g0][cc] * vv;
      a1 += pcs[g1][cc] * vv;
    }
    cmp_s[g0][e] = a0;
    cmp_s[g1][e] = a1;
  }
  __syncthreads();

  // ---- AvgPool(5,4,ceil) + stable top-16 (wave 0) ----
  if (tid < 64) {
    float pooled = -INFINITY;
    int myj = 63;
    if (tid < NBLK) {
      myj = tid;
      float sum = 0.f; int cnt = 0;
      for (int kp = 0; kp <= SBLKn / STRIDEn; ++kp) {
        int idx = tid * (SBLKn / STRIDEn) + kp;
        if (idx < C) { sum += score_s[idx]; cnt++; }
      }
      pooled = sum / (float)cnt;
    }
    unsigned long long msk = 0ull;
    for (int r = 0; r < NSELn; ++r) {
      float bv = pooled; int bi = myj;
      for (int off = 32; off; off >>= 1) {
        float ov = __shfl_xor(bv, off);
        int oi = __shfl_xor(bi, off);
        if (ov > bv || (ov == bv && oi < bi)) { bv = ov; bi = oi; }
      }
      msk |= (1ull << bi);
      if (myj == bi) pooled = -INFINITY;   // remove winner
    }
    if (tid == 0) selmask_s = msk;
  }
  __syncthreads();

  const unsigned long long msk = selmask_s;
  const int winlo = s - (WINn - 1);

  // ---- raw logits for needed blocks (selected OR intersects window) ----
  for (int t = tid; t <= s; t += 256) {
    const int j = t >> 6;
    const bool nb = ((msk >> j) & 1ull) || ((j * SBLKn + SBLKn - 1) >= winlo);
    if (!nb) continue;
    const float4* kr = (const float4*)(k + (t * HKn + hk) * Dn);
    float a0 = 0, a1 = 0, a2 = 0, a3 = 0;
#pragma unroll 4
    for (int d4 = 0; d4 < Dn / 4; ++d4) {
      float4 kk = kr[d4];
      const int d = d4 * 4;
      a0 += qs[0][d]*kk.x + qs[0][d+1]*kk.y + qs[0][d+2]*kk.z + qs[0][d+3]*kk.w;
      a1 += qs[1][d]*kk.x + qs[1][d+1]*kk.y + qs[1][d+2]*kk.z + qs[1][d+3]*kk.w;
      a2 += qs[2][d]*kk.x + qs[2][d+1]*kk.y + qs[2][d+2]*kk.z + qs[2][d+3]*kk.w;
      a3 += qs[3][d]*kk.x + qs[3][d+1]*kk.y + qs[3][d+2]*kk.z + qs[3][d+3]*kk.w;
    }
    lw[0][t] = a0 * scale; lw[1][t] = a1 * scale;
    lw[2][t] = a2 * scale; lw[3][t] = a3 * scale;
  }
  __syncthreads();

  // ---- softmax stats for sel and win paths (wave wid -> g) ----
  {
    const int g = wid;
    float msel = -INFINITY, mwin = -INFINITY;
    for (int t = lane; t <= s; t += 64) {
      const int j = t >> 6;
      const bool sb = (msk >> j) & 1ull;
      const bool wb = t >= winlo;
      if (!(sb | wb)) continue;
      const float x = lw[g][t];
      if (sb) msel = fmaxf(msel, x);
      if (wb) mwin = fmaxf(mwin, x);
    }
    for (int off = 32; off; off >>= 1) {
      msel = fmaxf(msel, __shfl_xor(msel, off));
      mwin = fmaxf(mwin, __shfl_xor(mwin, off));
    }
    float dsel = 0.f, dwin = 0.f;
    for (int t = lane; t <= s; t += 64) {
      const int j = t >> 6;
      const bool sb = (msk >> j) & 1ull;
      const bool wb = t >= winlo;
      if (!(sb | wb)) continue;
      const float x = lw[g][t];
      if (sb) dsel += expf(x - msel);
      if (wb) dwin += expf(x - mwin);
    }
    for (int off = 32; off; off >>= 1) {
      dsel += __shfl_xor(dsel, off);
      dwin += __shfl_xor(dwin, off);
    }
    if (lane == 0) {
      msum_s[g][0] = msel;
      msum_s[g][1] = 1.f / fmaxf(dsel, 1e-20f);
      msum_s[g][2] = mwin;
      msum_s[g][3] = 1.f / fmaxf(dwin, 1e-20f);
    }
  }
  __syncthreads();

  // ---- combined per-token weight: g0*p_sel + g1*p_win (in place) ----
  for (int t = tid; t <= s; t += 256) {
    const int j = t >> 6;
    const bool sb = (msk >> j) & 1ull;
    const bool nb = sb || ((j * SBLKn + SBLKn - 1) >= winlo);
    if (!nb) continue;
    const bool wb = t >= winlo;
#pragma unroll
    for (int g = 0; g < Gn; ++g) {
      const float x = lw[g][t];
      float w = 0.f;
      if (sb) w += gate_s[g][0] * expf(x - msum_s[g][0]) * msum_s[g][1];
      if (wb) w += gate_s[g][1] * expf(x - msum_s[g][2]) * msum_s[g][3];
      lw[g][t] = w;
    }
  }
  __syncthreads();

  // ---- PV over needed blocks + gated combine with compressed path ----
  {
    const int e = tid & 127, half = tid >> 7;
    const int g0 = 2 * half, g1 = g0 + 1;
    float a0 = 0.f, a1 = 0.f;
    const int jmax = s >> 6;
    for (int j = 0; j <= jmax; ++j) {
      const bool nb = ((msk >> j) & 1ull) || ((j * SBLKn + SBLKn - 1) >= winlo);
      if (!nb) continue;
      const int tend = min(j * SBLKn + SBLKn - 1, s);
      for (int t = j * SBLKn; t <= tend; ++t) {
        const float vv = v[(t * HKn + hk) * DVn + e];
        a0 += lw[g0][t] * vv;
        a1 += lw[g1][t] * vv;
      }
    }
    out[(s * HQn + hk * Gn + g0) * DVn + e] = a0 + gate_s[g0][2] * cmp_s[g0][e];
    out[(s * HQn + hk * Gn + g1) * DVn + e] = a1 + gate_s[g1][2] * cmp_s[g1][e];
  }
}

// ---------------------------------------------------------------------------
extern "C" void kernel_launch(void* const* d_in, const int* in_sizes, int n_in,
                              void* d_out, int out_size, void* d_ws, size_t ws_size,
                              hipStream_t stream) {
  const float* q  = (const float*)d_in[0];
  const float* k  = (const float*)d_in[1];
  const float* v  = (const float*)d_in[2];
  const float* Wk = (const float*)d_in[3];
  const float* Wv = (const float*)d_in[4];
  const float* Wg = (const float*)d_in[5];
  const float* bg = (const float*)d_in[6];
  // d_in[7] = cu_seqlens (bs=1), d_in[8] = max_seqlen — unused

  const int S = in_sizes[0] / (HQn * Dn);          // 2048
  const int C = (S - CBLKn) / STRIDEn + 1;         // 127
  const int NBLK = S / SBLKn;                      // 32

  float* ck = (float*)d_ws;
  float* cv = ck + (size_t)HKn * C * Dn;

  dim3 gA((C + 3) / 4, HKn);
  nsa_compress<<<gA, 128, 0, stream>>>(k, Wk, ck, S, C);
  nsa_compress<<<gA, 128, 0, stream>>>(v, Wv, cv, S, C);

  dim3 gC(S, HKn);
  nsa_main<<<gC, 256, 0, stream>>>(q, k, v, ck, cv, Wg, bg, (float*)d_out,
                                   S, C, NBLK);
}

// Round 2
// 441.776 us; speedup vs baseline: 5.0097x; 5.0097x over previous
//
#include <hip/hip_runtime.h>
#include <math.h>

#define HQn 16
#define HKn 4
#define Gn 4
#define Dn 128
#define STRIDEn 16
#define CBLKn 32
#define SBLKn 64
#define NSELn 16
#define WINn 512
#define Sn 2048
#define Cn 127
#define NBLKn 32
#define TS 16

typedef float f32x4 __attribute__((ext_vector_type(4)));
typedef __bf16 bf16x8 __attribute__((ext_vector_type(8)));
typedef unsigned short ushort8 __attribute__((ext_vector_type(8)));
typedef unsigned int uint2v __attribute__((ext_vector_type(2)));

__device__ inline unsigned short f2bf(float x) {
  union { float f; unsigned u; } a; a.f = x;
  unsigned r = a.u + 0x7fffu + ((a.u >> 16) & 1u);
  return (unsigned short)(r >> 16);
}

__device__ inline f32x4 mfma16(bf16x8 a, bf16x8 b, f32x4 c) {
  return __builtin_amdgcn_mfma_f32_16x16x32_bf16(a, b, c, 0, 0, 0);
}

// ---------------------------------------------------------------------------
// Compression partials: part[(which*4+fs)][h][c][e], f-split over fs (1024 f's
// each). 128 threads: c-group (tid>>5) x e-quad ((tid&31)*4). f32, no LDS.
// ---------------------------------------------------------------------------
__global__ __launch_bounds__(128)
void nsa_compress(const float* __restrict__ k, const float* __restrict__ v,
                  const float* __restrict__ Wk, const float* __restrict__ Wv,
                  float* __restrict__ part) {
  const int which = blockIdx.z >> 2;
  const int fs    = blockIdx.z & 3;
  const int h     = blockIdx.y;
  const int c     = blockIdx.x * 4 + (threadIdx.x >> 5);
  const int e0    = (threadIdx.x & 31) * 4;
  if (c >= Cn) return;
  const float* src = which ? v : k;
  const float* W   = which ? Wv : Wk;
  float a0 = 0.f, a1 = 0.f, a2 = 0.f, a3 = 0.f;
  const int w0 = fs * 8;
  for (int wi = 0; wi < 8; ++wi) {
    const int row = c * STRIDEn + w0 + wi;
    const float4* kr = (const float4*)(src + ((size_t)row * HKn + h) * Dn);
    const float* Wr = W + (size_t)(w0 + wi) * Dn * Dn;
#pragma unroll 4
    for (int d4 = 0; d4 < 32; ++d4) {
      float4 kk = kr[d4];
      float4 w0v = *(const float4*)(Wr + (size_t)(d4 * 4 + 0) * Dn + e0);
      float4 w1v = *(const float4*)(Wr + (size_t)(d4 * 4 + 1) * Dn + e0);
      float4 w2v = *(const float4*)(Wr + (size_t)(d4 * 4 + 2) * Dn + e0);
      float4 w3v = *(const float4*)(Wr + (size_t)(d4 * 4 + 3) * Dn + e0);
      a0 += kk.x * w0v.x + kk.y * w1v.x + kk.z * w2v.x + kk.w * w3v.x;
      a1 += kk.x * w0v.y + kk.y * w1v.y + kk.z * w2v.y + kk.w * w3v.y;
      a2 += kk.x * w0v.z + kk.y * w1v.z + kk.z * w2v.z + kk.w * w3v.z;
      a3 += kk.x * w0v.w + kk.y * w1v.w + kk.z * w2v.w + kk.w * w3v.w;
    }
  }
  float* d = part + (size_t)(which * 4 + fs) * (HKn * Cn * Dn)
                  + ((size_t)h * Cn + c) * Dn + e0;
  d[0] = a0; d[1] = a1; d[2] = a2; d[3] = a3;
}

__global__ void nsa_reduce(const float* __restrict__ part,
                           float* __restrict__ ck, float* __restrict__ cv) {
  const int i = blockIdx.x * 256 + threadIdx.x;
  const int N = HKn * Cn * Dn;
  if (i < N) {
    ck[i] = ((part[i] + part[(size_t)N + i]) + (part[2 * (size_t)N + i] + part[3 * (size_t)N + i]));
    cv[i] = ((part[4 * (size_t)N + i] + part[5 * (size_t)N + i]) + (part[6 * (size_t)N + i] + part[7 * (size_t)N + i]));
  }
}

// ---------------------------------------------------------------------------
// Compressed attention + selection + gates. Wave per row s; 4 rows per block.
// Writes selmask, gates (ws) and g2*cmp_o into d_out (kernel C accumulates).
// All f32 — identical selection math to the verified round-1 kernel.
// ---------------------------------------------------------------------------
__global__ __launch_bounds__(256)
void nsa_cmp_sel(const float* __restrict__ q, const float* __restrict__ ck,
                 const float* __restrict__ cv, const float* __restrict__ Wg,
                 const float* __restrict__ bg, float* __restrict__ gates,
                 unsigned long long* __restrict__ selm, float* __restrict__ out) {
  __shared__ float qs4[4][Gn][Dn];
  __shared__ float pcs2[4][128][4];
  __shared__ float score_l[4][128];
  __shared__ float gate2_l[4][Gn];
  const int wid = threadIdx.x >> 6, lane = threadIdx.x & 63;
  const int s = blockIdx.x * 4 + wid;
  const int hk = blockIdx.y;
  const float scale = 0.08838834764831845f;

  for (int i = lane; i < Gn * Dn; i += 64) {
    int g = i >> 7, d = i & 127;
    qs4[wid][g][d] = q[((size_t)s * HQn + hk * Gn + g) * Dn + d];
  }
  const int cmax = (s >= CBLKn - 1) ? ((s - (CBLKn - 1)) >> 4) + 1 : 0;

  float x0[4] = {0.f, 0.f, 0.f, 0.f}, x1[4] = {0.f, 0.f, 0.f, 0.f};
#pragma unroll
  for (int wh = 0; wh < 2; ++wh) {
    const int c = lane + wh * 64;
    float a0 = 0.f, a1 = 0.f, a2 = 0.f, a3 = 0.f;
    if (c < cmax) {
      const float4* ckr = (const float4*)(ck + ((size_t)hk * Cn + c) * Dn);
      for (int d4 = 0; d4 < 32; ++d4) {
        float4 kk = ckr[d4];
        float4 q0 = *(const float4*)&qs4[wid][0][d4 * 4];
        float4 q1 = *(const float4*)&qs4[wid][1][d4 * 4];
        float4 q2 = *(const float4*)&qs4[wid][2][d4 * 4];
        float4 q3 = *(const float4*)&qs4[wid][3][d4 * 4];
        a0 += kk.x * q0.x + kk.y * q0.y + kk.z * q0.z + kk.w * q0.w;
        a1 += kk.x * q1.x + kk.y * q1.y + kk.z * q1.z + kk.w * q1.w;
        a2 += kk.x * q2.x + kk.y * q2.y + kk.z * q2.z + kk.w * q2.w;
        a3 += kk.x * q3.x + kk.y * q3.y + kk.z * q3.z + kk.w * q3.w;
      }
    }
    if (wh == 0) { x0[0] = a0 * scale; x0[1] = a1 * scale; x0[2] = a2 * scale; x0[3] = a3 * scale; }
    else         { x1[0] = a0 * scale; x1[1] = a1 * scale; x1[2] = a2 * scale; x1[3] = a3 * scale; }
  }
  // masked softmax per g over c
  float p0[4], p1[4];
#pragma unroll
  for (int g = 0; g < 4; ++g) {
    float m = -1e30f;
    if (lane < cmax) m = x0[g];
    if (lane + 64 < cmax) m = fmaxf(m, x1[g]);
    for (int off = 32; off; off >>= 1) m = fmaxf(m, __shfl_xor(m, off));
    float e0v = (lane < cmax) ? __expf(x0[g] - m) : 0.f;
    float e1v = (lane + 64 < cmax) ? __expf(x1[g] - m) : 0.f;
    float sum = e0v + e1v;
    for (int off = 32; off; off >>= 1) sum += __shfl_xor(sum, off);
    float inv = 1.f / fmaxf(sum, 1e-20f);
    p0[g] = e0v * inv; p1[g] = e1v * inv;
  }
  {
    float4 v0 = {p0[0], p0[1], p0[2], p0[3]};
    float4 v1 = {p1[0], p1[1], p1[2], p1[3]};
    *(float4*)&pcs2[wid][lane][0] = v0;
    *(float4*)&pcs2[wid][lane + 64][0] = v1;
    score_l[wid][lane] = v0.x + v0.y + v0.z + v0.w;
    score_l[wid][lane + 64] = v1.x + v1.y + v1.z + v1.w;
  }
  // pooled AvgPool(5,4,ceil) + stable top-16
  float pooled; int myj;
  if (lane < NBLKn) {
    myj = lane; float sum = 0.f; int cnt = 0;
    for (int kp = 0; kp <= 4; ++kp) {
      int idx = lane * 4 + kp;
      if (idx < Cn) { sum += score_l[wid][idx]; cnt++; }
    }
    pooled = sum / (float)cnt;
  } else { myj = 63; pooled = -INFINITY; }
  unsigned long long msk = 0ull;
  for (int r = 0; r < NSELn; ++r) {
    float bv = pooled; int bi = myj;
    for (int off = 32; off; off >>= 1) {
      float ov = __shfl_xor(bv, off); int oi = __shfl_xor(bi, off);
      if (ov > bv || (ov == bv && oi < bi)) { bv = ov; bi = oi; }
    }
    msk |= (1ull << bi);
    if (myj == bi) pooled = -INFINITY;
  }
  if (lane == 0) selm[(size_t)s * HKn + hk] = msk;
  // gates
  if (lane < 12) {
    int g = lane / 3, j = lane % 3;
    float a = bg[j];
    for (int d = 0; d < Dn; ++d) a += qs4[wid][g][d] * Wg[d * 3 + j];
    float gv = 1.f / (1.f + __expf(-a));
    gates[((size_t)s * HQn + hk * Gn + g) * 3 + j] = gv;
    if (j == 2) gate2_l[wid][g] = gv;
  }
  // compressed PV, pre-gated into out
  {
    float b0[4] = {0.f, 0.f, 0.f, 0.f}, b1[4] = {0.f, 0.f, 0.f, 0.f};
    for (int cc = 0; cc < cmax; ++cc) {
      float4 pp = *(const float4*)&pcs2[wid][cc][0];
      float v1 = cv[((size_t)hk * Cn + cc) * Dn + lane];
      float v2 = cv[((size_t)hk * Cn + cc) * Dn + lane + 64];
      b0[0] += pp.x * v1; b0[1] += pp.y * v1; b0[2] += pp.z * v1; b0[3] += pp.w * v1;
      b1[0] += pp.x * v2; b1[1] += pp.y * v2; b1[2] += pp.z * v2; b1[3] += pp.w * v2;
    }
#pragma unroll
    for (int g = 0; g < 4; ++g) {
      float g2 = gate2_l[wid][g];
      out[((size_t)s * HQn + hk * Gn + g) * Dn + lane] = g2 * b0[g];
      out[((size_t)s * HQn + hk * Gn + g) * Dn + lane + 64] = g2 * b1[g];
    }
  }
}

// ---------------------------------------------------------------------------
// MFMA sel+win attention. Block = (16 s-rows, kv-head); 4 waves = 4 GQA heads.
// Two-pass: stats then combined-weight PV. Swapped QK (D = K*Q^T) so P is
// token-contiguous; V staged transposed. out += result (cmp part already there).
// ---------------------------------------------------------------------------
#define Q_OFF 0
#define K_OFF 16384
#define V_OFF 32768
#define P_OFF 49152

__global__ __launch_bounds__(256)
void nsa_attn(const float* __restrict__ q, const float* __restrict__ k,
              const float* __restrict__ v, const float* __restrict__ gates,
              const unsigned long long* __restrict__ selm,
              float* __restrict__ out) {
  __shared__ __align__(16) char smem[57344];
  __shared__ unsigned long long sm_row[TS];
  __shared__ int blist[34];
  __shared__ int nbl_s;

  const int tid = threadIdx.x;
  const int lane = tid & 63;
  const int w = tid >> 6;            // GQA head g
  const int h4 = lane >> 4;
  const int cl = lane & 15;
  const int s0 = blockIdx.x * TS;
  const int hk = blockIdx.y;
  const int sw = (lane & 7) << 4;
  const float scale = 0.08838834764831845f;

  if (tid < TS) sm_row[tid] = selm[(size_t)(s0 + tid) * HKn + hk];
  __syncthreads();

  if (tid == 0) {
    unsigned long long un = 0ull;
    for (int i = 0; i < TS; ++i) un |= sm_row[i];
    const int jmax = (s0 + TS - 1) >> 6;
    const int wlo = s0 - (WINn - 1);
    int n = 0;
    for (int j = 0; j <= jmax; ++j)
      if (((un >> j) & 1ull) || (j * 64 + 63 >= wlo)) blist[n++] = j;
    nbl_s = n;
  }

  // stage Q (pre-scaled) bf16, swizzled rows r = g*16 + ls
  {
    const int r = tid >> 2, dc = (tid & 3) * 32;
    const int g = r >> 4, ls = r & 15;
    const float4* s4 = (const float4*)(q + ((size_t)(s0 + ls) * HQn + hk * Gn + g) * Dn + dc);
#pragma unroll
    for (int ch = 0; ch < 4; ++ch) {
      float4 a = s4[ch * 2], b = s4[ch * 2 + 1];
      ushort8 u;
      u[0] = f2bf(a.x * scale); u[1] = f2bf(a.y * scale); u[2] = f2bf(a.z * scale); u[3] = f2bf(a.w * scale);
      u[4] = f2bf(b.x * scale); u[5] = f2bf(b.y * scale); u[6] = f2bf(b.z * scale); u[7] = f2bf(b.w * scale);
      *(ushort8*)(smem + Q_OFF + r * 256 + (((dc + ch * 8) * 2) ^ ((r & 7) << 4))) = u;
    }
  }
  __syncthreads();

  const int nbl = nbl_s;
  const int srow = s0 + cl;
  const unsigned long long mymask = sm_row[cl];

  bf16x8 qb[4];
#pragma unroll
  for (int ks = 0; ks < 4; ++ks)
    qb[ks] = __builtin_bit_cast(bf16x8,
        *(const ushort8*)(smem + Q_OFF + (w * 16 + cl) * 256 + ((ks * 64 + h4 * 16) ^ sw)));

  auto stageK = [&]() {
    const int tl = tid >> 2, dc = (tid & 3) * 32;
    const int tb_l = blist[0]; (void)tb_l;
    return;
  };
  (void)stageK;

  float m = -1e30f, dsel = 0.f, dwin = 0.f;

  // ---------------- pass 1: per-row stats ----------------
  for (int bi = 0; bi < nbl; ++bi) {
    const int j = blist[bi];
    const int tb = j * 64;
    __syncthreads();
    {
      const int tl = tid >> 2, dc = (tid & 3) * 32;
      const float4* s4 = (const float4*)(k + ((size_t)(tb + tl) * HKn + hk) * Dn + dc);
#pragma unroll
      for (int ch = 0; ch < 4; ++ch) {
        float4 a = s4[ch * 2], b = s4[ch * 2 + 1];
        ushort8 u;
        u[0] = f2bf(a.x); u[1] = f2bf(a.y); u[2] = f2bf(a.z); u[3] = f2bf(a.w);
        u[4] = f2bf(b.x); u[5] = f2bf(b.y); u[6] = f2bf(b.z); u[7] = f2bf(b.w);
        *(ushort8*)(smem + K_OFF + tl * 256 + (((dc + ch * 8) * 2) ^ ((tl & 7) << 4))) = u;
      }
    }
    __syncthreads();
    const bool selb = (mymask >> j) & 1ull;
    float xr[16]; unsigned vm_s = 0, vm_w = 0;
#pragma unroll
    for (int mt = 0; mt < 4; ++mt) {
      f32x4 acc = {0.f, 0.f, 0.f, 0.f};
#pragma unroll
      for (int ks = 0; ks < 4; ++ks) {
        bf16x8 ka = __builtin_bit_cast(bf16x8,
            *(const ushort8*)(smem + K_OFF + (mt * 16 + cl) * 256 + ((ks * 64 + h4 * 16) ^ sw)));
        acc = mfma16(ka, qb[ks], acc);
      }
#pragma unroll
      for (int r = 0; r < 4; ++r) {
        const int token = tb + mt * 16 + h4 * 4 + r;
        xr[mt * 4 + r] = acc[r];
        const bool cz = token <= srow;
        if (cz && selb) vm_s |= 1u << (mt * 4 + r);
        if (cz && (srow - token) < WINn) vm_w |= 1u << (mt * 4 + r);
      }
    }
    const unsigned vm = vm_s | vm_w;
    float bm = -1e30f;
#pragma unroll
    for (int i = 0; i < 16; ++i) bm = fmaxf(bm, ((vm >> i) & 1u) ? xr[i] : -1e30f);
    const float mn = fmaxf(m, bm);
    const float sc = __expf(m - mn);
    dsel *= sc; dwin *= sc;
#pragma unroll
    for (int i = 0; i < 16; ++i) {
      const float e = __expf(xr[i] - mn);
      dsel += ((vm_s >> i) & 1u) ? e : 0.f;
      dwin += ((vm_w >> i) & 1u) ? e : 0.f;
    }
    m = mn;
  }
  // merge across the 4 lane-groups holding the same row
#pragma unroll
  for (int off = 16; off <= 32; off <<= 1) {
    float mo = __shfl_xor(m, off);
    float ds = __shfl_xor(dsel, off);
    float dw = __shfl_xor(dwin, off);
    float mn = fmaxf(m, mo);
    float s1 = __expf(m - mn), s2 = __expf(mo - mn);
    dsel = dsel * s1 + ds * s2;
    dwin = dwin * s1 + dw * s2;
    m = mn;
  }

  const float g0 = gates[((size_t)srow * HQn + hk * Gn + w) * 3 + 0];
  const float g1 = gates[((size_t)srow * HQn + hk * Gn + w) * 3 + 1];
  const float Acf = g0 / fmaxf(dsel, 1e-20f);
  const float Bcf = g1 / fmaxf(dwin, 1e-20f);

  f32x4 oacc[8];
#pragma unroll
  for (int em = 0; em < 8; ++em) { f32x4 z = {0.f, 0.f, 0.f, 0.f}; oacc[em] = z; }

  // ---------------- pass 2: combined weights + PV ----------------
  for (int bi = 0; bi < nbl; ++bi) {
    const int j = blist[bi];
    const int tb = j * 64;
    __syncthreads();
    {
      const int tl = tid >> 2, dc = (tid & 3) * 32;
      const float4* s4 = (const float4*)(k + ((size_t)(tb + tl) * HKn + hk) * Dn + dc);
#pragma unroll
      for (int ch = 0; ch < 4; ++ch) {
        float4 a = s4[ch * 2], b = s4[ch * 2 + 1];
        ushort8 u;
        u[0] = f2bf(a.x); u[1] = f2bf(a.y); u[2] = f2bf(a.z); u[3] = f2bf(a.w);
        u[4] = f2bf(b.x); u[5] = f2bf(b.y); u[6] = f2bf(b.z); u[7] = f2bf(b.w);
        *(ushort8*)(smem + K_OFF + tl * 256 + (((dc + ch * 8) * 2) ^ ((tl & 7) << 4))) = u;
      }
    }
    {
      const int p2 = tid & 31, eg = tid >> 5;
      const int t0 = p2 * 2, e0 = eg * 16;
      const float4* r0 = (const float4*)(v + ((size_t)(tb + t0) * HKn + hk) * Dn + e0);
      const float4* r1 = (const float4*)(v + ((size_t)(tb + t0 + 1) * HKn + hk) * Dn + e0);
      float va[16], vb[16]; float4 t;
      t = r0[0]; va[0] = t.x; va[1] = t.y; va[2] = t.z; va[3] = t.w;
      t = r0[1]; va[4] = t.x; va[5] = t.y; va[6] = t.z; va[7] = t.w;
      t = r0[2]; va[8] = t.x; va[9] = t.y; va[10] = t.z; va[11] = t.w;
      t = r0[3]; va[12] = t.x; va[13] = t.y; va[14] = t.z; va[15] = t.w;
      t = r1[0]; vb[0] = t.x; vb[1] = t.y; vb[2] = t.z; vb[3] = t.w;
      t = r1[1]; vb[4] = t.x; vb[5] = t.y; vb[6] = t.z; vb[7] = t.w;
      t = r1[2]; vb[8] = t.x; vb[9] = t.y; vb[10] = t.z; vb[11] = t.w;
      t = r1[3]; vb[12] = t.x; vb[13] = t.y; vb[14] = t.z; vb[15] = t.w;
#pragma unroll
      for (int e = 0; e < 16; ++e) {
        unsigned u = (unsigned)f2bf(va[e]) | ((unsigned)f2bf(vb[e]) << 16);
        *(unsigned*)(smem + V_OFF + (e0 + e) * 128 + ((t0 * 2) ^ (((e0 + e) & 7) << 4))) = u;
      }
    }
    __syncthreads();
    const bool selb = (mymask >> j) & 1ull;
#pragma unroll
    for (int mt = 0; mt < 4; ++mt) {
      f32x4 acc = {0.f, 0.f, 0.f, 0.f};
#pragma unroll
      for (int ks = 0; ks < 4; ++ks) {
        bf16x8 ka = __builtin_bit_cast(bf16x8,
            *(const ushort8*)(smem + K_OFF + (mt * 16 + cl) * 256 + ((ks * 64 + h4 * 16) ^ sw)));
        acc = mfma16(ka, qb[ks], acc);
      }
      unsigned short pw[4];
#pragma unroll
      for (int r = 0; r < 4; ++r) {
        const int token = tb + mt * 16 + h4 * 4 + r;
        const bool cz = token <= srow;
        const float e = __expf(acc[r] - m);
        const float cf = ((cz && selb) ? Acf : 0.f)
                       + ((cz && (srow - token) < WINn) ? Bcf : 0.f);
        pw[r] = f2bf(e * cf);
      }
      uint2v pu;
      pu[0] = (unsigned)pw[0] | ((unsigned)pw[1] << 16);
      pu[1] = (unsigned)pw[2] | ((unsigned)pw[3] << 16);
      *(uint2v*)(smem + P_OFF + w * 2048 + cl * 128 + (((mt * 16 + h4 * 4) * 2) ^ sw)) = pu;
    }
    bf16x8 pb0 = __builtin_bit_cast(bf16x8,
        *(const ushort8*)(smem + P_OFF + w * 2048 + cl * 128 + ((h4 * 16) ^ sw)));
    bf16x8 pb1 = __builtin_bit_cast(bf16x8,
        *(const ushort8*)(smem + P_OFF + w * 2048 + cl * 128 + ((64 + h4 * 16) ^ sw)));
#pragma unroll
    for (int em = 0; em < 8; ++em) {
      bf16x8 va0 = __builtin_bit_cast(bf16x8,
          *(const ushort8*)(smem + V_OFF + (em * 16 + cl) * 128 + ((h4 * 16) ^ sw)));
      bf16x8 va1 = __builtin_bit_cast(bf16x8,
          *(const ushort8*)(smem + V_OFF + (em * 16 + cl) * 128 + ((64 + h4 * 16) ^ sw)));
      oacc[em] = mfma16(va0, pb0, oacc[em]);
      oacc[em] = mfma16(va1, pb1, oacc[em]);
    }
  }

  // ---------------- epilogue: transpose via LDS, accumulate into out ----------
  __syncthreads();
  float* o_l = (float*)(smem + 16384);
#pragma unroll
  for (int em = 0; em < 8; ++em)
#pragma unroll
    for (int r = 0; r < 4; ++r)
      o_l[(w * 16 + cl) * 129 + em * 16 + h4 * 4 + r] = oacc[em][r];
  __syncthreads();
  {
    const int rr = tid >> 2, dc = (tid & 3) * 32;
    const int g = rr >> 4, ls = rr & 15;
    const size_t rowoff = ((size_t)(s0 + ls) * HQn + hk * Gn + g) * Dn + dc;
    float4* ou = (float4*)(out + rowoff);
#pragma unroll
    for (int i = 0; i < 8; ++i) {
      float4 cc = ou[i];
      float4 r;
      r.x = o_l[rr * 129 + dc + i * 4 + 0] + cc.x;
      r.y = o_l[rr * 129 + dc + i * 4 + 1] + cc.y;
      r.z = o_l[rr * 129 + dc + i * 4 + 2] + cc.z;
      r.w = o_l[rr * 129 + dc + i * 4 + 3] + cc.w;
      ou[i] = r;
    }
  }
}

// ---------------------------------------------------------------------------
extern "C" void kernel_launch(void* const* d_in, const int* in_sizes, int n_in,
                              void* d_out, int out_size, void* d_ws, size_t ws_size,
                              hipStream_t stream) {
  const float* q  = (const float*)d_in[0];
  const float* k  = (const float*)d_in[1];
  const float* v  = (const float*)d_in[2];
  const float* Wk = (const float*)d_in[3];
  const float* Wv = (const float*)d_in[4];
  const float* Wg = (const float*)d_in[5];
  const float* bg = (const float*)d_in[6];
  float* out = (float*)d_out;

  const int N = HKn * Cn * Dn;  // 65024
  float* part  = (float*)d_ws;                 // 8*N
  float* ck    = part + (size_t)8 * N;
  float* cv    = ck + N;
  float* gates = cv + N;                       // S*HQ*3
  unsigned long long* selm =
      (unsigned long long*)(gates + (size_t)Sn * HQn * 3);

  nsa_compress<<<dim3(32, HKn, 8), 128, 0, stream>>>(k, v, Wk, Wv, part);
  nsa_reduce<<<dim3((N + 255) / 256), 256, 0, stream>>>(part, ck, cv);
  nsa_cmp_sel<<<dim3(Sn / 4, HKn), 256, 0, stream>>>(q, ck, cv, Wg, bg, gates, selm, out);
  nsa_attn<<<dim3(Sn / TS, HKn), 256, 0, stream>>>(q, k, v, gates, selm, out);
}